// Round 2
// baseline (81.890 us; speedup 1.0000x reference)
//
#include <hip/hip_runtime.h>

// MultiPositiveContrastiveLoss: B=32768 problems, C=64 candidates, P=16 pos, N=48 neg.
// One wave handles 8 problems. C == wavefront size, so lane l loads scores[b*64+l]
// COALESCED, and the index-gather is a single ds_bpermute (__shfl with dynamic lane)
// instead of a dependent global gather. The pos loop is fully unrolled over P=16 with
// +/-1e30 sentinels for invalid slots (their relu terms are exactly 0), so the
// broadcasts compile to v_readlane_b32 with constant lane indices.

#define MARGIN 0.5f

constexpr int C = 64;
constexpr int P = 16;
constexpr int N = 48;
constexpr int BLOCK = 256;
constexpr int WAVES_PER_BLOCK = BLOCK / 64;                        // 4
constexpr int PROBS_PER_WAVE = 8;
constexpr int PROBS_PER_BLOCK = WAVES_PER_BLOCK * PROBS_PER_WAVE;  // 32

__global__ __launch_bounds__(BLOCK) void mpcl_partial_kernel(
    const float* __restrict__ scores,
    const int*   __restrict__ pos_indices,
    const int*   __restrict__ neg_indices,
    const int*   __restrict__ pos_counts,
    const int*   __restrict__ neg_counts,
    float2*      __restrict__ partials,
    int B)
{
    const int lane = threadIdx.x & 63;
    const int wave = threadIdx.x >> 6;

    float tot = 0.0f;
    float cnt = 0.0f;

    const int b0 = (blockIdx.x * WAVES_PER_BLOCK + wave) * PROBS_PER_WAVE;

    #pragma unroll
    for (int k = 0; k < PROBS_PER_WAVE; ++k) {
        const int b = b0 + k;
        const bool valid = (b < B);

        int   pc = 0, nc = 0;
        float sc = 0.0f;   // this lane's candidate score (coalesced load)
        int   idx = 0;     // this lane's pos/neg index (coalesced load)
        if (valid) {
            pc  = pos_counts[b];
            nc  = neg_counts[b];
            sc  = scores[b * C + lane];                       // fully coalesced, C==64
            idx = (lane < N) ? neg_indices[b * N + lane]      // lanes 0..47: neg slot
                             : pos_indices[b * P + (lane - N)]; // lanes 48..63: pos slot
        }

        // in-register gather: score at this lane's index
        const float g = __shfl(sc, idx);                      // one ds_bpermute

        // sentinels make invalid pairs contribute exactly 0 through the relu
        const float myval  = (lane >= N) ? (((lane - N) < pc) ? g : 1e30f) : 0.0f;
        const float negval = (lane <  N) ? ((lane < nc) ? g : -1e30f) : -1e30f;

        float s0 = 0.0f, s1 = 0.0f;                           // 2 accumulators for ILP
        #pragma unroll
        for (int i = 0; i < P; i += 2) {
            const float p0 = __shfl(myval, N + i);            // constant lane -> v_readlane
            const float p1 = __shfl(myval, N + i + 1);
            s0 += fmaxf(MARGIN - p0 + negval, 0.0f);
            s1 += fmaxf(MARGIN - p1 + negval, 0.0f);
        }
        tot += s0 + s1;
        cnt += (float)(pc * nc);                              // closed-form pair count
    }

    // wave reduce total (cnt is wave-uniform already)
    #pragma unroll
    for (int off = 32; off; off >>= 1) tot += __shfl_xor(tot, off);

    __shared__ float2 lds[WAVES_PER_BLOCK];
    if (lane == 0) lds[wave] = make_float2(tot, cnt);
    __syncthreads();

    if (threadIdx.x == 0) {
        float2 acc = lds[0];
        #pragma unroll
        for (int w = 1; w < WAVES_PER_BLOCK; ++w) { acc.x += lds[w].x; acc.y += lds[w].y; }
        partials[blockIdx.x] = acc;
    }
}

__global__ __launch_bounds__(BLOCK) void mpcl_final_kernel(
    const float2* __restrict__ partials, int n, float* __restrict__ out)
{
    float tot = 0.0f, cnt = 0.0f;
    for (int i = threadIdx.x; i < n; i += BLOCK) {
        const float2 p = partials[i];
        tot += p.x;
        cnt += p.y;
    }
    #pragma unroll
    for (int off = 32; off; off >>= 1) {
        tot += __shfl_xor(tot, off);
        cnt += __shfl_xor(cnt, off);
    }

    __shared__ float2 lds[WAVES_PER_BLOCK];
    const int wave = threadIdx.x >> 6;
    const int lane = threadIdx.x & 63;
    if (lane == 0) lds[wave] = make_float2(tot, cnt);
    __syncthreads();

    if (threadIdx.x == 0) {
        float T = 0.0f, Cn = 0.0f;
        #pragma unroll
        for (int w = 0; w < WAVES_PER_BLOCK; ++w) { T += lds[w].x; Cn += lds[w].y; }
        out[0] = (Cn > 0.0f) ? (T / fmaxf(Cn, 1.0f)) : 0.0f;
    }
}

extern "C" void kernel_launch(void* const* d_in, const int* in_sizes, int n_in,
                              void* d_out, int out_size, void* d_ws, size_t ws_size,
                              hipStream_t stream) {
    const float* scores      = (const float*)d_in[0];
    const int*   pos_indices = (const int*)d_in[1];
    const int*   neg_indices = (const int*)d_in[2];
    const int*   pos_counts  = (const int*)d_in[3];
    const int*   neg_counts  = (const int*)d_in[4];
    float*       out         = (float*)d_out;

    const int B = in_sizes[3];                                        // 32768
    const int grid = (B + PROBS_PER_BLOCK - 1) / PROBS_PER_BLOCK;     // 1024

    float2* partials = (float2*)d_ws;                                 // 1024 * 8 B

    mpcl_partial_kernel<<<grid, BLOCK, 0, stream>>>(
        scores, pos_indices, neg_indices, pos_counts, neg_counts, partials, B);
    mpcl_final_kernel<<<1, BLOCK, 0, stream>>>(partials, grid, out);
}